// Round 1
// baseline (245.840 us; speedup 1.0000x reference)
//
#include <hip/hip_runtime.h>

#define DIM 128
#define CLIPV 6.0f

// One pair (positive or negative) per 32-lane group.
// lane i loads float4 at element i*4 of each 128-dim row -> 32*4 = 128 elems.
__global__ void __launch_bounds__(256) sg_loss_kernel(
    const float* __restrict__ u_emb,
    const float* __restrict__ v_emb,
    const int*  __restrict__ nodes,
    const int*  __restrict__ posu,
    const int*  __restrict__ posv,
    const int*  __restrict__ negu,
    const int*  __restrict__ negv,
    int n_pos, int n_neg,
    float* __restrict__ out)
{
    const int lane = threadIdx.x & 31;   // lane within 32-group
    const int grp  = threadIdx.x >> 5;   // 0..7 groups per block
    const int p    = blockIdx.x * 8 + grp;
    const int P    = n_pos + n_neg;

    float contrib = 0.0f;
    if (p < P) {
        int iu, iv; float sgn;
        if (p < n_pos) {
            iu = posu[p]; iv = posv[p]; sgn = 1.0f;
        } else {
            int q = p - n_pos;
            iu = negu[q]; iv = negv[q]; sgn = -1.0f;
        }
        const long long ru = (long long)nodes[iu] * DIM;
        const long long rv = (long long)nodes[iv] * DIM;
        const float4 a = *reinterpret_cast<const float4*>(u_emb + ru + lane * 4);
        const float4 b = *reinterpret_cast<const float4*>(v_emb + rv + lane * 4);
        float s = a.x * b.x + a.y * b.y + a.z * b.z + a.w * b.w;
        // 32-lane butterfly reduce (masks < 32 stay within the half-wave)
        s += __shfl_xor(s, 1);
        s += __shfl_xor(s, 2);
        s += __shfl_xor(s, 4);
        s += __shfl_xor(s, 8);
        s += __shfl_xor(s, 16);
        // clip then -log_sigmoid(sgn * s) = log(1 + exp(-sgn*s))
        s = fminf(fmaxf(s, -CLIPV), CLIPV);
        const float x = sgn * s;
        contrib = logf(1.0f + expf(-x));
    }

    // block reduction: lane 0 of each 32-group holds the full contribution
    __shared__ float smem[8];
    if (lane == 0) smem[grp] = contrib;
    __syncthreads();
    if (threadIdx.x == 0) {
        float t = 0.0f;
#pragma unroll
        for (int i = 0; i < 8; ++i) t += smem[i];
        atomicAdd(out, t);
    }
}

extern "C" void kernel_launch(void* const* d_in, const int* in_sizes, int n_in,
                              void* d_out, int out_size, void* d_ws, size_t ws_size,
                              hipStream_t stream) {
    const float* u_emb = (const float*)d_in[0];
    const float* v_emb = (const float*)d_in[1];
    const int*   nodes = (const int*)d_in[2];
    const int*   posu  = (const int*)d_in[3];
    const int*   posv  = (const int*)d_in[4];
    const int*   negu  = (const int*)d_in[5];
    const int*   negv  = (const int*)d_in[6];
    const int n_pos = in_sizes[3];
    const int n_neg = in_sizes[5];
    const int P = n_pos + n_neg;

    float* out = (float*)d_out;
    // d_out is poisoned once and never re-zeroed between replays: zero it here.
    hipMemsetAsync(out, 0, sizeof(float), stream);

    const int blocks = (P + 7) / 8;  // 8 pairs per 256-thread block
    sg_loss_kernel<<<blocks, 256, 0, stream>>>(
        u_emb, v_emb, nodes, posu, posv, negu, negv, n_pos, n_neg, out);
}

// Round 2
// 23.300 us; speedup vs baseline: 10.5509x; 10.5509x over previous
//
#include <hip/hip_runtime.h>

#define DIM 128
#define CLIPV 6.0f
#define TPB 256
#define NBLK 1024

// Stage 1: one pair per 32-lane group, grid-strided; per-block partial sums.
// lane i loads float4 at element i*4 of each 128-dim row (32*4 = 128 elems).
__global__ void __launch_bounds__(TPB) sg_pair_partial(
    const float* __restrict__ u_emb,
    const float* __restrict__ v_emb,
    const int*  __restrict__ nodes,
    const int*  __restrict__ posu,
    const int*  __restrict__ posv,
    const int*  __restrict__ negu,
    const int*  __restrict__ negv,
    int n_pos, int n_neg,
    float* __restrict__ partial)
{
    const int lane = threadIdx.x & 31;
    const int grp  = threadIdx.x >> 5;          // 8 groups / block
    const int ngrp = gridDim.x * (TPB >> 5);    // total 32-lane groups
    const int P    = n_pos + n_neg;

    float acc = 0.0f;  // identical across the 32 lanes of the group
    for (int p = blockIdx.x * (TPB >> 5) + grp; p < P; p += ngrp) {
        int iu, iv; float sgn;
        if (p < n_pos) {
            iu = posu[p]; iv = posv[p]; sgn = 1.0f;
        } else {
            const int q = p - n_pos;
            iu = negu[q]; iv = negv[q]; sgn = -1.0f;
        }
        const float4 a = *reinterpret_cast<const float4*>(
            u_emb + (long long)nodes[iu] * DIM + lane * 4);
        const float4 b = *reinterpret_cast<const float4*>(
            v_emb + (long long)nodes[iv] * DIM + lane * 4);
        float s = a.x * b.x + a.y * b.y + a.z * b.z + a.w * b.w;
        s += __shfl_xor(s, 1);
        s += __shfl_xor(s, 2);
        s += __shfl_xor(s, 4);
        s += __shfl_xor(s, 8);
        s += __shfl_xor(s, 16);
        s = fminf(fmaxf(s, -CLIPV), CLIPV);
        const float x = sgn * s;                 // -log_sigmoid(x) = log(1+e^-x)
        acc += __logf(1.0f + __expf(-x));
    }

    __shared__ float smem[TPB / 32];
    if (lane == 0) smem[grp] = acc;
    __syncthreads();
    if (threadIdx.x == 0) {
        float t = 0.0f;
#pragma unroll
        for (int i = 0; i < TPB / 32; ++i) t += smem[i];
        partial[blockIdx.x] = t;                 // plain store, no atomics
    }
}

// Stage 2: single block reduces NBLK partials and WRITES the scalar output
// (no accumulate -> no zero-init / memset needed).
__global__ void __launch_bounds__(1024) sg_reduce(
    const float* __restrict__ partial, int n, float* __restrict__ out)
{
    float t = 0.0f;
    for (int i = threadIdx.x; i < n; i += 1024) t += partial[i];
    // wave64 butterfly
    t += __shfl_xor(t, 1);
    t += __shfl_xor(t, 2);
    t += __shfl_xor(t, 4);
    t += __shfl_xor(t, 8);
    t += __shfl_xor(t, 16);
    t += __shfl_xor(t, 32);
    __shared__ float smem[16];
    if ((threadIdx.x & 63) == 0) smem[threadIdx.x >> 6] = t;
    __syncthreads();
    if (threadIdx.x == 0) {
        float s = 0.0f;
#pragma unroll
        for (int i = 0; i < 16; ++i) s += smem[i];
        out[0] = s;
    }
}

extern "C" void kernel_launch(void* const* d_in, const int* in_sizes, int n_in,
                              void* d_out, int out_size, void* d_ws, size_t ws_size,
                              hipStream_t stream) {
    const float* u_emb = (const float*)d_in[0];
    const float* v_emb = (const float*)d_in[1];
    const int*   nodes = (const int*)d_in[2];
    const int*   posu  = (const int*)d_in[3];
    const int*   posv  = (const int*)d_in[4];
    const int*   negu  = (const int*)d_in[5];
    const int*   negv  = (const int*)d_in[6];
    const int n_pos = in_sizes[3];
    const int n_neg = in_sizes[5];

    float* partial = (float*)d_ws;   // NBLK floats of scratch
    float* out     = (float*)d_out;

    sg_pair_partial<<<NBLK, TPB, 0, stream>>>(
        u_emb, v_emb, nodes, posu, posv, negu, negv, n_pos, n_neg, partial);
    sg_reduce<<<1, 1024, 0, stream>>>(partial, NBLK, out);
}

// Round 4
// 17.446 us; speedup vs baseline: 14.0916x; 1.3356x over previous
//
#include <hip/hip_runtime.h>

#define DIM 128
#define LANES 8                 // lanes per pair; 16 elems (4 float4) per lane
#define TPB 256
#define NBLK 1024
#define CLIPV 6.0f

__global__ void __launch_bounds__(TPB) sg_pair_partial(
    const float* __restrict__ u_emb,
    const float* __restrict__ v_emb,
    const int*  __restrict__ nodes,
    const int*  __restrict__ posu,
    const int*  __restrict__ posv,
    const int*  __restrict__ negu,
    const int*  __restrict__ negv,
    int n_pos, int n_neg,
    float* __restrict__ partial)
{
    const int lane = threadIdx.x & (LANES - 1);     // 0..7 within pair-group
    const int grp  = threadIdx.x / LANES;           // 0..31 groups per block
    const int gid  = blockIdx.x * (TPB / LANES) + grp;
    const int ngrp = gridDim.x * (TPB / LANES);
    const int P    = n_pos + n_neg;

    float acc = 0.0f;   // replicated across the 8 lanes of the group
    for (int p = gid; p < P; p += ngrp) {
        int iu, iv; float sgn;
        if (p < n_pos) {
            iu = posu[p]; iv = posv[p]; sgn = 1.0f;
        } else {
            const int q = p - n_pos;
            iu = negu[q]; iv = negv[q]; sgn = -1.0f;
        }
        // 32-bit row offsets: nodes < 1e6, *128 < 2^31
        const float* ra = u_emb + (unsigned)nodes[iu] * DIM + lane * 16;
        const float* rb = v_emb + (unsigned)nodes[iv] * DIM + lane * 16;
        const float4 a0 = *reinterpret_cast<const float4*>(ra + 0);
        const float4 a1 = *reinterpret_cast<const float4*>(ra + 4);
        const float4 a2 = *reinterpret_cast<const float4*>(ra + 8);
        const float4 a3 = *reinterpret_cast<const float4*>(ra + 12);
        const float4 b0 = *reinterpret_cast<const float4*>(rb + 0);
        const float4 b1 = *reinterpret_cast<const float4*>(rb + 4);
        const float4 b2 = *reinterpret_cast<const float4*>(rb + 8);
        const float4 b3 = *reinterpret_cast<const float4*>(rb + 12);
        float s = a0.x * b0.x + a0.y * b0.y + a0.z * b0.z + a0.w * b0.w;
        s += a1.x * b1.x + a1.y * b1.y + a1.z * b1.z + a1.w * b1.w;
        s += a2.x * b2.x + a2.y * b2.y + a2.z * b2.z + a2.w * b2.w;
        s += a3.x * b3.x + a3.y * b3.y + a3.z * b3.z + a3.w * b3.w;
        // 8-lane butterfly
        s += __shfl_xor(s, 1);
        s += __shfl_xor(s, 2);
        s += __shfl_xor(s, 4);
        s = fminf(fmaxf(s, -CLIPV), CLIPV);
        acc += __logf(1.0f + __expf(-sgn * s));   // -log_sigmoid(sgn*s)
    }

    // Fold across the wave: xor 8/16/32 sums exactly ONE lane from each of the
    // 8 groups (lanes l, l^8, ..., l^56 all have the same lane&7) -> each
    // pair counted exactly once. No rescale.
    float t = acc;
    t += __shfl_xor(t, 8);
    t += __shfl_xor(t, 16);
    t += __shfl_xor(t, 32);
    __shared__ float smem[TPB / 64];
    if ((threadIdx.x & 63) == 0) smem[threadIdx.x >> 6] = t;
    __syncthreads();
    if (threadIdx.x == 0) {
        float b = 0.0f;
#pragma unroll
        for (int i = 0; i < TPB / 64; ++i) b += smem[i];
        partial[blockIdx.x] = b;                  // plain store, no atomics
    }
}

// Stage 2: one 256-thread block; reads NBLK floats as float4 and writes out[0].
__global__ void __launch_bounds__(256) sg_reduce(
    const float* __restrict__ partial, float* __restrict__ out)
{
    const float4 v = reinterpret_cast<const float4*>(partial)[threadIdx.x];
    float t = v.x + v.y + v.z + v.w;
    t += __shfl_xor(t, 1);
    t += __shfl_xor(t, 2);
    t += __shfl_xor(t, 4);
    t += __shfl_xor(t, 8);
    t += __shfl_xor(t, 16);
    t += __shfl_xor(t, 32);
    __shared__ float smem[4];
    if ((threadIdx.x & 63) == 0) smem[threadIdx.x >> 6] = t;
    __syncthreads();
    if (threadIdx.x == 0) out[0] = smem[0] + smem[1] + smem[2] + smem[3];
}

extern "C" void kernel_launch(void* const* d_in, const int* in_sizes, int n_in,
                              void* d_out, int out_size, void* d_ws, size_t ws_size,
                              hipStream_t stream) {
    const float* u_emb = (const float*)d_in[0];
    const float* v_emb = (const float*)d_in[1];
    const int*   nodes = (const int*)d_in[2];
    const int*   posu  = (const int*)d_in[3];
    const int*   posv  = (const int*)d_in[4];
    const int*   negu  = (const int*)d_in[5];
    const int*   negv  = (const int*)d_in[6];
    const int n_pos = in_sizes[3];
    const int n_neg = in_sizes[5];

    float* partial = (float*)d_ws;   // NBLK floats of scratch
    float* out     = (float*)d_out;

    sg_pair_partial<<<NBLK, TPB, 0, stream>>>(
        u_emb, v_emb, nodes, posu, posv, negu, negv, n_pos, n_neg, partial);
    sg_reduce<<<1, 256, 0, stream>>>(partial, out);
}